// Round 10
// baseline (309.090 us; speedup 1.0000x reference)
//
#include <hip/hip_runtime.h>

// LocallyConnected2D: y[n,h,w] = relu(sum_{i,j} x[n,h+i,w+j]*W[h,w,i,j] + b[h,w])
// History (key points):
//  R9: lane=n, readlane+fma, XOR-swizzled LDS, 172us. Best of direct family.
//  R10/R11: reg-array prefetch -> spill (357us). R12: DMA ring -> 274us.
//  R13: H_T=8 16w/CU: FETCH -58MB, FLAT. R14: 24w/CU: occ 51%, FLAT.
//  R15: s_load weights: VALUBusy 53->10.6% -> calibrates VALUBusy as
//      per-SIMD issue; readlane hazard ~= 2.5x instr count. Time UP (K$).
//  R16: persistent + ring + held-reg prefetch: 181us, FLAT.
//  Conclusion: traffic, TLP, pipelining, cold-start all varied -> floor
//      172-187us invariant. Realized HBM BW pinned 1.0-2.0 TB/s in EVERY
//      variant (streaming ceiling 6.3): every global access is a 64-line
//      scatter (lane=n, n-stride 1MB) -> random-64B-granule DRAM ceiling.
//      292MB / ~1.7TB/s = 172us = the floor. Layout, not scheduling.
//  R17 (this): kill the scatter.
//      K1: x[n][h][w] -> x_T[h][w][n] in d_ws (REQUIRES ws >= 64MB); both
//          sides coalesced via LDS tile (reads 256B/n, writes 16KB blocks).
//      K2: R13 frame; staging reads x_T row-slabs: 4KB CONTIGUOUS per row,
//          linear LDS writes, no swizzle (n-contiguous layout conflict-free
//          for lane=n b32 reads). Weights gather unchanged (dense region,
//          never the scatter problem). Stores stay scattered (63.5MB exact,
//          fire-and-forget). Readlanes BLOCKED (8 indep readlane, then 8
//          fmac) to kill the VALU->SGPR->VALU hazard padding.

#define H_IN 512
#define W_IN 512
#define H_OUT 504
#define W_OUT 504
#define W_T 8
#define H_T 8
#define TROWS 16              // staged input rows
#define XF (TROWS * 1024)     // 16384 floats = 64 KB -> 2 blocks/CU
#define NTX 63
#define NTY 63
#define NBLK (NTX * NTY)      // 3969

__device__ __forceinline__ float readlane_f(float v, int l) {
    return __int_as_float(__builtin_amdgcn_readlane(__float_as_int(v), l));
}

// ---- kernel 1: x[n][h][w] -> xt[h][w][n]; both sides coalesced via LDS ----
__launch_bounds__(256, 4)
__global__ void xpose_kernel(const float* __restrict__ x,
                             float* __restrict__ xt) {
    __shared__ float tl[64 * 68];         // [n][w-64, pad 68 floats]
    const int t  = threadIdx.x;
    const int h  = blockIdx.x;            // 0..511
    const int w0 = blockIdx.y << 6;       // 0..448

    {   // read x[n, h, w0 + c*16 .. +15]: 256B contiguous per n
        const int n = t >> 2, c = t & 3;
        const float* g = x + (size_t)n * (H_IN * W_IN)
                           + (size_t)h * W_IN + w0 + c * 16;
        float* l = &tl[n * 68 + c * 16];  // (n*68+c*16)*4B: 16B-aligned
        #pragma unroll
        for (int j = 0; j < 4; ++j)
            *reinterpret_cast<float4*>(l + j * 4) =
                *reinterpret_cast<const float4*>(g + j * 4);
    }
    __syncthreads();
    {   // write xt[h, w0+wl, 0..63]: block stores 16KB contiguous
        const int wl = t >> 2, seg = t & 3;
        float o[16];
        #pragma unroll
        for (int k = 0; k < 16; ++k)
            o[k] = tl[(seg * 16 + k) * 68 + wl];
        float* g = xt + ((size_t)h * W_IN + w0 + wl) * 64 + seg * 16;
        #pragma unroll
        for (int j = 0; j < 4; ++j)
            *reinterpret_cast<float4*>(g + j * 4) =
                make_float4(o[4 * j], o[4 * j + 1], o[4 * j + 2], o[4 * j + 3]);
    }
}

// ---- kernel 2: main compute from x_T ----
__launch_bounds__(512, 2)
__global__ void lc2d_kernel(const float* __restrict__ xt,
                            const float* __restrict__ weight,
                            const float* __restrict__ bias,
                            float* __restrict__ out) {
    __shared__ float lds[XF];   // [row 0..15][w-j 0..15][n 0..63], linear

    const int t    = threadIdx.x;
    const int lane = t & 63;          // batch index n (compute phase)
    const int wv   = t >> 6;          // wave 0..7

    // bijective XCD swizzle: ty-adjacent tiles (share 8 x_T rows) -> same XCD
    int swz;
    {
        const int bid = blockIdx.x;
        const int xcd = bid & 7, i = bid >> 3;
        const int q = NBLK >> 3, r = NBLK & 7;          // 496, 1
        swz = (xcd < r ? xcd * (q + 1)
                       : r * (q + 1) + (xcd - r) * q) + i;
    }
    const int ty = swz % NTY;
    const int tx = swz / NTY;
    const int h0 = ty * H_T;
    const int w0 = tx * W_T;

    // ---- stage x tile: 16 rows x 4KB, each row a CONTIGUOUS x_T slab ----
    // thread t: row = t>>5, i = t&31; 8 reps of float4. LDS write linear.
    {
        const int row = t >> 5;
        const int i   = t & 31;
        const float* g = xt + ((size_t)(h0 + row) * W_IN + w0) * 64 + i * 4;
        float* l = &lds[row * 1024 + i * 4];
        #pragma unroll
        for (int rep = 0; rep < 8; ++rep)
            *reinterpret_cast<float4*>(l + rep * 128) =
                *reinterpret_cast<const float4*>(g + rep * 128);
    }

    // ---- weights: per-wave gather -> 18 VGPRs, packed p = q*16 + rr ----
    float wpk[18];
    {
        const float* wb = weight + ((size_t)(h0 + wv) * W_OUT + w0) * 81;
        const int qb = lane >> 4;     // 0..3
        const int rr = lane & 15;
        #pragma unroll
        for (int d = 0; d < 18; ++d) {
            const int q  = 4 * d + qb;        // 0..71
            const int k  = q / 9;             // magic-mul
            const int tp = q - 9 * k;
            float v = 0.f;
            if (rr < 9) v = __builtin_nontemporal_load(wb + k * 81 + rr * 9 + tp);
            wpk[d] = v;
        }
    }

    __syncthreads();

    const int wvu = __builtin_amdgcn_readfirstlane(wv);
    const int h   = h0 + wvu;                      // this wave's output row

    float acc[W_T];
    {
        const float* bptr = bias + (size_t)h * W_OUT + w0;   // uniform: s_load
        #pragma unroll
        for (int k = 0; k < W_T; ++k) acc[k] = bptr[k];
    }

    const float* xb = &lds[lane];     // + rb + j*64 per read

    #pragma unroll 1
    for (int r = 0; r < 9; ++r) {
        // x row (wvu + r): 16 b32 reads, n-contiguous -> conflict-free
        const int rb = (wvu + r) * 1024;
        float xr[16];
        #pragma unroll
        for (int j = 0; j < 16; ++j)
            xr[j] = xb[rb + j * 64];

        const int li0 = r;
        const int li1 = r + 16;
        const int li2 = r + 32;
        const int li3 = r + 48;

        // BLOCKED broadcast: 8 independent readlanes, then 8 fmacs
        // (dependency distance 8 kills the VALU->SGPR->VALU hazard pad)
        #pragma unroll
        for (int tp = 0; tp < 9; ++tp) {
            float wsv[W_T];
            #pragma unroll
            for (int k = 0; k < W_T; ++k) {
                const int q  = k * 9 + tp;          // compile-time
                const int qm = q & 3;
                const int li = (qm == 0) ? li0 : (qm == 1) ? li1
                             : (qm == 2) ? li2 : li3;
                wsv[k] = readlane_f(wpk[q >> 2], li);
            }
            #pragma unroll
            for (int k = 0; k < W_T; ++k)
                acc[k] = fmaf(wsv[k], xr[k + tp], acc[k]);
        }
    }

    // ---- epilogue: ReLU + regular stores ----
    float* o = out + (size_t)lane * (H_OUT * W_OUT) + (size_t)h * W_OUT + w0;
    float4 s;
    s.x = fmaxf(acc[0], 0.f); s.y = fmaxf(acc[1], 0.f);
    s.z = fmaxf(acc[2], 0.f); s.w = fmaxf(acc[3], 0.f);
    *reinterpret_cast<float4*>(o) = s;
    s.x = fmaxf(acc[4], 0.f); s.y = fmaxf(acc[5], 0.f);
    s.z = fmaxf(acc[6], 0.f); s.w = fmaxf(acc[7], 0.f);
    *reinterpret_cast<float4*>(o + 4) = s;
}

extern "C" void kernel_launch(void* const* d_in, const int* in_sizes, int n_in,
                              void* d_out, int out_size, void* d_ws, size_t ws_size,
                              hipStream_t stream) {
    const float* x      = (const float*)d_in[0];
    const float* weight = (const float*)d_in[1];
    const float* bias   = (const float*)d_in[2];
    float* out          = (float*)d_out;
    float* xt           = (float*)d_ws;   // REQUIRES ws_size >= 512*512*64*4 = 64MB

    xpose_kernel<<<dim3(H_IN, W_IN / 64), 256, 0, stream>>>(x, xt);
    lc2d_kernel<<<dim3(NBLK), 512, 0, stream>>>(xt, weight, bias, out);
}